// Round 2
// baseline (487.036 us; speedup 1.0000x reference)
//
#include <hip/hip_runtime.h>

typedef unsigned short u16;
typedef short short8 __attribute__((ext_vector_type(8)));
typedef float f32x4 __attribute__((ext_vector_type(4)));

// ---------------- helpers ----------------
__device__ __forceinline__ u16 f2b(float f) {
  unsigned u = __float_as_uint(f);
  u = u + 0x7FFFu + ((u >> 16) & 1u);   // round-to-nearest-even
  return (u16)(u >> 16);
}
__device__ __forceinline__ float b2f(u16 b) {
  return __uint_as_float(((unsigned)b) << 16);
}

#define ASYNC_LD16(g, l)                                                                   \
  __builtin_amdgcn_global_load_lds((const __attribute__((address_space(1))) void*)(g),     \
                                   (__attribute__((address_space(3))) void*)(l), 16, 0, 0)

// raw barrier with compiler memory fences on both sides
#define BAR()                                  \
  do {                                         \
    asm volatile("" ::: "memory");             \
    __builtin_amdgcn_s_barrier();              \
    asm volatile("" ::: "memory");             \
  } while (0)

// ---------------- K0a: x fp32 -> bf16 ----------------
__global__ void convert_x(const float* __restrict__ x, u16* __restrict__ xb) {
  size_t i = ((size_t)blockIdx.x * 256 + threadIdx.x) * 4;
  float4 f = *(const float4*)(x + i);
  ushort4 o;
  o.x = f2b(f.x); o.y = f2b(f.y); o.z = f2b(f.z); o.w = f2b(f.w);
  *(ushort4*)(xb + i) = o;
}

// ---------------- K0b: weights fp32 -> bf16 (natural [o][e] layout) ----------------
__global__ void convert_w(const float* __restrict__ Wq, const float* __restrict__ Wk,
                          const float* __restrict__ Wv, const float* __restrict__ Wo,
                          u16* __restrict__ Wqkv, u16* __restrict__ Wob) {
  int idx = (blockIdx.x * 256 + threadIdx.x) * 4;
  int row = idx >> 9;
  int col = idx & 511;
  const float* src = (row < 512)    ? Wq + (size_t)row * 512
                     : (row < 1024) ? Wk + (size_t)(row - 512) * 512
                     : (row < 1536) ? Wv + (size_t)(row - 1024) * 512
                                    : Wo + (size_t)(row - 1536) * 512;
  u16* dst = (row < 1536) ? Wqkv + (size_t)row * 512 : Wob + (size_t)(row - 1536) * 512;
  float4 f = *(const float4*)(src + col);
  ushort4 o;
  o.x = f2b(f.x); o.y = f2b(f.y); o.z = f2b(f.z); o.w = f2b(f.w);
  *(ushort4*)(dst + col) = o;
}

// ================= 256x256 pipelined GEMM core (shared by K1 and K3) =================
// 512 threads = 8 waves (2 M x 4 N), per-wave C = 128x64. BK=32, 16 K-tiles.
// 4 LDS buffers x 32KB = 128KB. Depth-3 prefetch: tile t+3 staged while computing
// tile t -> ~2 tiles (~900-1200 cy) of load flight; boundary wait is vmcnt(8),
// never 0 until drain (T3+T4).
// Granule XOR-swizzle g ^= (row>>1)&3 on the GLOBAL source of global_load_lds
// (LDS dest stays linear, rule #21) and identically on the ds_read side.
// Bank check (quarter-wave, 16 lanes): quad = 16*(lr&1) + 4*(qd^((lr>>1)&3));
// same-half lanes {lr, lr+2, ..} spread across all 4 quads, 2 rows/bank = free.
//
// Expected in-scope names: tid, S, Asrc0, Asrc1, Bsrc0, Bsrc1, rbA, rbB, acc.

#define STAGE_A(buf, kt)                                                 \
  do {                                                                   \
    ASYNC_LD16(Asrc0 + (kt) * 32, S + (buf) * 16384 + tid * 8);          \
    ASYNC_LD16(Asrc1 + (kt) * 32, S + (buf) * 16384 + 4096 + tid * 8);   \
  } while (0)
#define STAGE_B(buf, kt)                                                 \
  do {                                                                   \
    ASYNC_LD16(Bsrc0 + (kt) * 32, S + (buf) * 16384 + 8192 + tid * 8);   \
    ASYNC_LD16(Bsrc1 + (kt) * 32, S + (buf) * 16384 + 12288 + tid * 8);  \
  } while (0)

#define GEMM_MAIN_LOOP()                                                                     \
  STAGE_A(0, 0); STAGE_B(0, 0);                                                              \
  STAGE_A(1, 1); STAGE_B(1, 1);                                                              \
  STAGE_A(2, 2); STAGE_B(2, 2);                                                              \
  asm volatile("s_waitcnt vmcnt(8)" ::: "memory"); /* tile0's 4 loads landed */              \
  BAR();                                                                                     \
  for (int t = 0; t < 16; ++t) {                                                             \
    const u16* Ab = S + (t & 3) * 16384;                                                     \
    const int nb = (t + 3) & 3;                                                              \
    short8 bf[4], af[4];                                                                     \
    /* ---- phase 0: B-frags + A-frags m0..3, prefetch A of tile t+3 ---- */                 \
    if (t < 13) STAGE_A(nb, t + 3);                                                          \
    _Pragma("unroll") for (int j = 0; j < 4; ++j) bf[j] = *(const short8*)&Ab[rbB + j * 512];\
    _Pragma("unroll") for (int m = 0; m < 4; ++m) af[m] = *(const short8*)&Ab[rbA + m * 512];\
    BAR();                                                                                   \
    __builtin_amdgcn_s_setprio(1);                                                           \
    _Pragma("unroll") for (int m = 0; m < 4; ++m)                                            \
      _Pragma("unroll") for (int j = 0; j < 4; ++j)                                          \
        acc[m][j] = __builtin_amdgcn_mfma_f32_16x16x32_bf16(af[m], bf[j], acc[m][j], 0, 0, 0);\
    __builtin_amdgcn_s_setprio(0);                                                           \
    /* ---- phase 1: A-frags m4..7, prefetch B of tile t+3 ---- */                           \
    if (t < 13) STAGE_B(nb, t + 3);                                                          \
    _Pragma("unroll") for (int m = 0; m < 4; ++m)                                            \
        af[m] = *(const short8*)&Ab[rbA + (m + 4) * 512];                                    \
    BAR();                                                                                   \
    __builtin_amdgcn_s_setprio(1);                                                           \
    _Pragma("unroll") for (int m = 0; m < 4; ++m)                                            \
      _Pragma("unroll") for (int j = 0; j < 4; ++j)                                          \
        acc[m + 4][j] =                                                                      \
            __builtin_amdgcn_mfma_f32_16x16x32_bf16(af[m], bf[j], acc[m + 4][j], 0, 0, 0);   \
    __builtin_amdgcn_s_setprio(0);                                                           \
    /* ---- tile boundary: tile t+1 must be landed; keep t+2,t+3 loads in flight ---- */     \
    if (t < 13)      asm volatile("s_waitcnt vmcnt(8)" ::: "memory");                        \
    else if (t == 13) asm volatile("s_waitcnt vmcnt(4)" ::: "memory");                       \
    else             asm volatile("s_waitcnt vmcnt(0)" ::: "memory");                        \
    BAR();                                                                                   \
  }

// ---------------- K1: fused QKV projection ----------------
// Q written token-major [tok][512]; K,V written TRANSPOSED per (b,r): [br][chan][tok]
__global__ __launch_bounds__(512, 2) void gemm_qkv(
    const u16* __restrict__ xb, const u16* __restrict__ Wqkv,
    const float* __restrict__ bq, const float* __restrict__ bk,
    const float* __restrict__ bv, u16* __restrict__ Qb,
    u16* __restrict__ Ktg, u16* __restrict__ Vtg) {
  __shared__ u16 S[65536];  // 128 KB: 4 bufs x (A 256x32 + B 256x32) bf16
  const int tid = threadIdx.x;
  // XCD-bijective swizzle: nwg = 1536 = 8 * 192; n-tile inner so 6 consecutive wgs
  // share one 256-row A panel (L2 reuse).
  const int bid = blockIdx.x;
  const int wg = (bid & 7) * 192 + (bid >> 3);
  const int mtile = wg / 6;
  const int ntile = wg - mtile * 6;
  const int blockM = mtile << 8;
  const int blockN = ntile << 8;

  const int lane = tid & 63;
  const int w = tid >> 6;
  const int wm = (w >> 2) << 7;  // 0 / 128
  const int wn = (w & 3) << 6;   // 0 / 64 / 128 / 192
  const int lr = lane & 15;
  const int qd = lane >> 4;

  // staging: thread tid owns LDS granule (row = tid>>2, g = tid&3) of each 128-row half;
  // source granule pre-swizzled: g_src = (tid&3) ^ ((row>>1)&3)  (matches read side)
  const int srow = tid >> 2;
  const int sg = (tid & 3) ^ ((tid >> 3) & 3);
  const u16* Asrc0 = xb + (size_t)(blockM + srow) * 512 + sg * 8;
  const u16* Asrc1 = Asrc0 + 128 * 512;
  const u16* Bsrc0 = Wqkv + (size_t)(blockN + srow) * 512 + sg * 8;
  const u16* Bsrc1 = Bsrc0 + 128 * 512;

  // ds_read bases (u16 units): row*32 + swizzled granule; frag m/j at +m*512/+j*512
  // (fragment row strides are multiples of 16 -> swizzle depends only on lr)
  const int gsw = (qd ^ ((lr >> 1) & 3)) * 8;
  const int rbA = (wm + lr) * 32 + gsw;
  const int rbB = 8192 + (wn + lr) * 32 + gsw;

  f32x4 acc[8][4];
#pragma unroll
  for (int m = 0; m < 8; ++m)
#pragma unroll
    for (int j = 0; j < 4; ++j) acc[m][j] = {0.f, 0.f, 0.f, 0.f};

  GEMM_MAIN_LOOP();

  // ---------------- epilogue ----------------
  const int which = blockN >> 9;   // ntile 0,1 -> Q; 2,3 -> K; 4,5 -> V
  const int cb = blockN & 511;
  if (which == 0) {
    // Q: token-major, elu+1
#pragma unroll
    for (int j = 0; j < 4; ++j) {
      int col = cb + wn + j * 16 + lr;
      float bsv = bq[col];
#pragma unroll
      for (int m = 0; m < 8; ++m) {
        int row = blockM + wm + m * 16 + qd * 4;
#pragma unroll
        for (int r = 0; r < 4; ++r) {
          float v = acc[m][j][r] + bsv;
          v = (v > 0.f) ? v + 1.f : __expf(v);
          Qb[(size_t)(row + r) * 512 + col] = f2b(v);
        }
      }
    }
  } else {
    // K/V: transposed store [br][chan][tok], elu+1 for K only
    u16* dstT = (which == 1) ? Ktg : Vtg;
    const float* bias = (which == 1) ? bk : bv;
    const int br = blockM >> 9;
    const int t0 = (blockM & 511) + wm;
#pragma unroll
    for (int j = 0; j < 4; ++j) {
      int col = cb + wn + j * 16 + lr;
      float bsv = bias[col];
      size_t rowbase = (size_t)br * 262144 + (size_t)col * 512;
#pragma unroll
      for (int m = 0; m < 8; ++m) {
        int c0 = t0 + m * 16 + qd * 4;
        float v0 = acc[m][j][0] + bsv, v1 = acc[m][j][1] + bsv;
        float v2 = acc[m][j][2] + bsv, v3 = acc[m][j][3] + bsv;
        if (which == 1) {
          v0 = (v0 > 0.f) ? v0 + 1.f : __expf(v0);
          v1 = (v1 > 0.f) ? v1 + 1.f : __expf(v1);
          v2 = (v2 > 0.f) ? v2 + 1.f : __expf(v2);
          v3 = (v3 > 0.f) ? v3 + 1.f : __expf(v3);
        }
        ushort4 p;
        p.x = f2b(v0); p.y = f2b(v1); p.z = f2b(v2); p.w = f2b(v3);
        *(ushort4*)&dstT[rowbase + c0] = p;
      }
    }
  }
}

// ---------------- K2: per (b,r,h): ktv, ksum, z, out_h — MFMA version ----------------
// Ktg/Vtg are [br][512 chan][512 tok]; Qb token-major; Hb token-major.
__global__ void attn(const u16* __restrict__ Qb, const u16* __restrict__ Ktg,
                     const u16* __restrict__ Vtg, u16* __restrict__ Hb) {
  __shared__ u16 KtS[64 * 32];     // [d][32 c]
  __shared__ u16 VtS[64 * 32];     // [e][32 c]
  __shared__ u16 QS[2 * 128 * 32]; // [kc][tok][32 d]
  __shared__ u16 ktvT[2 * 64 * 32];// [kc][e][32 d]  (bf16)
  __shared__ float part[256];
  __shared__ float ksumf[64];
  __shared__ float zs[128];

  const int tid = threadIdx.x;
  const int br = blockIdx.x >> 3;
  const int h = blockIdx.x & 7;
  const int h64 = h * 64;
  const size_t tok0 = (size_t)br * 512;
  const size_t tbase = (size_t)br * 262144 + (size_t)h64 * 512;

  const int lane = tid & 63;
  const int w = tid >> 6;
  const int lr = lane & 15;
  const int qd = lane >> 4;

  const int sc_chan = tid >> 2, sc_seg = tid & 3;  // staging: 64 chans x 4 segs of 8

  // ---------- phase A: ktv = K^T V (wave w owns d-strip [w*16, w*16+16)) ----------
  f32x4 acc[4];
#pragma unroll
  for (int j = 0; j < 4; ++j) acc[j] = {0.f, 0.f, 0.f, 0.f};
  float ks = 0.f;

  for (int ct = 0; ct < 16; ++ct) {
    __syncthreads();
    {
      size_t g = tbase + (size_t)sc_chan * 512 + ct * 32 + sc_seg * 8;
      ASYNC_LD16(Ktg + g, KtS + tid * 8);
      ASYNC_LD16(Vtg + g, VtS + tid * 8);
    }
    __syncthreads();
    short8 a = *(const short8*)&KtS[(w * 16 + lr) * 32 + qd * 8];
#pragma unroll
    for (int j = 0; j < 4; ++j) {
      short8 b = *(const short8*)&VtS[(j * 16 + lr) * 32 + qd * 8];
      acc[j] = __builtin_amdgcn_mfma_f32_16x16x32_bf16(a, b, acc[j], 0, 0, 0);
    }
    // ksum partial: thread owns (d = tid>>2, quarter cq = tid&3)
    ushort4 k0 = *(const ushort4*)&KtS[sc_chan * 32 + sc_seg * 8];
    ushort4 k1 = *(const ushort4*)&KtS[sc_chan * 32 + sc_seg * 8 + 4];
    ks += b2f(k0.x) + b2f(k0.y) + b2f(k0.z) + b2f(k0.w)
        + b2f(k1.x) + b2f(k1.y) + b2f(k1.z) + b2f(k1.w);
  }
  part[tid] = ks;
  // write ktvT [kc = w>>1][e][d' = (w&1)*16 + qd*4 + r] as bf16
  {
    int kc = w >> 1;
    int dp = (w & 1) * 16 + qd * 4;
#pragma unroll
    for (int j = 0; j < 4; ++j) {
      int e = j * 16 + lr;
      ushort4 p;
      p.x = f2b(acc[j][0]); p.y = f2b(acc[j][1]);
      p.z = f2b(acc[j][2]); p.w = f2b(acc[j][3]);
      *(ushort4*)&ktvT[kc * 2048 + e * 32 + dp] = p;
    }
  }
  __syncthreads();
  if (tid < 64)
    ksumf[tid] = part[tid * 4] + part[tid * 4 + 1] + part[tid * 4 + 2] + part[tid * 4 + 3];
  __syncthreads();

  // hoist B-fragments (ktv) — loop-invariant
  short8 bfr[4][2];
#pragma unroll
  for (int j = 0; j < 4; ++j)
#pragma unroll
    for (int kc = 0; kc < 2; ++kc)
      bfr[j][kc] = *(const short8*)&ktvT[kc * 2048 + (j * 16 + lr) * 32 + qd * 8];

  // ---------- phase B: out = (Q @ ktv) * z, 4 chunks of 128 tokens ----------
  for (int ct = 0; ct < 4; ++ct) {
    __syncthreads();
#pragma unroll
    for (int kc = 0; kc < 2; ++kc)
#pragma unroll
      for (int half = 0; half < 2; ++half)
        ASYNC_LD16(Qb + (tok0 + ct * 128 + half * 64 + sc_chan) * 512 + h64 + kc * 32 + sc_seg * 8,
                   QS + kc * 4096 + half * 2048 + tid * 8);
    __syncthreads();
    // z per token (skewed LDS walk, conflict-free)
    if (tid < 128) {
      float s = 0.f;
#pragma unroll 8
      for (int i = 0; i < 32; ++i) {
        int ix = (i + tid) & 31;
        s += b2f(QS[tid * 32 + ix]) * ksumf[ix];
        s += b2f(QS[4096 + tid * 32 + ix]) * ksumf[32 + ix];
      }
      zs[tid] = 1.f / (s + 1e-6f);
    }
    __syncthreads();
    // MFMA: wave w owns token strips (w*2+s)*16
#pragma unroll
    for (int s = 0; s < 2; ++s) {
      int mrow = (w * 2 + s) * 16 + lr;
      short8 a0 = *(const short8*)&QS[mrow * 32 + qd * 8];
      short8 a1 = *(const short8*)&QS[4096 + mrow * 32 + qd * 8];
      f32x4 o[4];
#pragma unroll
      for (int j = 0; j < 4; ++j) {
        o[j] = {0.f, 0.f, 0.f, 0.f};
        o[j] = __builtin_amdgcn_mfma_f32_16x16x32_bf16(a0, bfr[j][0], o[j], 0, 0, 0);
        o[j] = __builtin_amdgcn_mfma_f32_16x16x32_bf16(a1, bfr[j][1], o[j], 0, 0, 0);
      }
      int tl = (w * 2 + s) * 16 + qd * 4;
      float z0 = zs[tl], z1 = zs[tl + 1], z2 = zs[tl + 2], z3 = zs[tl + 3];
      size_t gb = (tok0 + ct * 128 + tl) * 512 + h64;
#pragma unroll
      for (int j = 0; j < 4; ++j) {
        int e = j * 16 + lr;
        Hb[gb + e] = f2b(o[j][0] * z0);
        Hb[gb + 512 + e] = f2b(o[j][1] * z1);
        Hb[gb + 1024 + e] = f2b(o[j][2] * z2);
        Hb[gb + 1536 + e] = f2b(o[j][3] * z3);
      }
    }
  }
}

// ---------------- K3: out = out_h @ Wo^T + bo (fp32 out) ----------------
__global__ __launch_bounds__(512, 2) void gemm_out(
    const u16* __restrict__ Hb, const u16* __restrict__ Wob,
    const float* __restrict__ bo, float* __restrict__ out) {
  __shared__ u16 S[65536];
  const int tid = threadIdx.x;
  // XCD-bijective swizzle: nwg = 512 = 8 * 64
  const int bid = blockIdx.x;
  const int wg = (bid & 7) * 64 + (bid >> 3);
  const int mtile = wg >> 1;
  const int ntile = wg & 1;
  const int blockM = mtile << 8;
  const int blockN = ntile << 8;

  const int lane = tid & 63;
  const int w = tid >> 6;
  const int wm = (w >> 2) << 7;
  const int wn = (w & 3) << 6;
  const int lr = lane & 15;
  const int qd = lane >> 4;

  const int srow = tid >> 2;
  const int sg = (tid & 3) ^ ((tid >> 3) & 3);
  const u16* Asrc0 = Hb + (size_t)(blockM + srow) * 512 + sg * 8;
  const u16* Asrc1 = Asrc0 + 128 * 512;
  const u16* Bsrc0 = Wob + (size_t)(blockN + srow) * 512 + sg * 8;
  const u16* Bsrc1 = Bsrc0 + 128 * 512;

  const int gsw = (qd ^ ((lr >> 1) & 3)) * 8;
  const int rbA = (wm + lr) * 32 + gsw;
  const int rbB = 8192 + (wn + lr) * 32 + gsw;

  f32x4 acc[8][4];
#pragma unroll
  for (int m = 0; m < 8; ++m)
#pragma unroll
    for (int j = 0; j < 4; ++j) acc[m][j] = {0.f, 0.f, 0.f, 0.f};

  GEMM_MAIN_LOOP();

#pragma unroll
  for (int j = 0; j < 4; ++j) {
    int col = blockN + wn + j * 16 + lr;
    float bsv = bo[col];
#pragma unroll
    for (int m = 0; m < 8; ++m) {
      int row = blockM + wm + m * 16 + qd * 4;
#pragma unroll
      for (int r = 0; r < 4; ++r)
        out[(size_t)(row + r) * 512 + col] = acc[m][j][r] + bsv;
    }
  }
}

// ---------------- launch ----------------
extern "C" void kernel_launch(void* const* d_in, const int* in_sizes, int n_in,
                              void* d_out, int out_size, void* d_ws, size_t ws_size,
                              hipStream_t stream) {
  const float* x  = (const float*)d_in[0];
  const float* Wq = (const float*)d_in[1];
  const float* bq = (const float*)d_in[2];
  const float* Wk = (const float*)d_in[3];
  const float* bk = (const float*)d_in[4];
  const float* Wv = (const float*)d_in[5];
  const float* bv = (const float*)d_in[6];
  const float* Wo = (const float*)d_in[7];
  const float* bo = (const float*)d_in[8];
  float* out = (float*)d_out;

  char* ws = (char*)d_ws;
  u16* xb   = (u16*)(ws);                 // 64 MB  (reused as Hb)
  u16* Wqkv = (u16*)(ws + 0x04000000ull); // 1.5 MB
  u16* Wob  = (u16*)(ws + 0x04200000ull); // 0.5 MB
  u16* Qb   = (u16*)(ws + 0x04400000ull); // 64 MB
  u16* Ktg  = (u16*)(ws + 0x08400000ull); // 64 MB [br][chan][tok]
  u16* Vtg  = (u16*)(ws + 0x0C400000ull); // 64 MB [br][chan][tok]
  u16* Hb   = xb;

  hipLaunchKernelGGL(convert_x, dim3(32768), dim3(256), 0, stream, x, xb);
  hipLaunchKernelGGL(convert_w, dim3(1024), dim3(256), 0, stream, Wq, Wk, Wv, Wo, Wqkv, Wob);
  hipLaunchKernelGGL(gemm_qkv, dim3(1536), dim3(512), 0, stream, xb, Wqkv, bq, bk, bv, Qb, Ktg, Vtg);
  hipLaunchKernelGGL(attn, dim3(1024), dim3(256), 0, stream, Qb, Ktg, Vtg, Hb);
  hipLaunchKernelGGL(gemm_out, dim3(512), dim3(512), 0, stream, Hb, Wob, bo, out);
}

// Round 4
// 465.613 us; speedup vs baseline: 1.0460x; 1.0460x over previous
//
#include <hip/hip_runtime.h>

typedef unsigned short u16;
typedef short short8 __attribute__((ext_vector_type(8)));
typedef float f32x4 __attribute__((ext_vector_type(4)));

// ---------------- helpers ----------------
__device__ __forceinline__ u16 f2b(float f) {
  unsigned u = __float_as_uint(f);
  u = u + 0x7FFFu + ((u >> 16) & 1u);   // round-to-nearest-even
  return (u16)(u >> 16);
}
__device__ __forceinline__ float b2f(u16 b) {
  return __uint_as_float(((unsigned)b) << 16);
}

#define ASYNC_LD16(g, l)                                                                   \
  __builtin_amdgcn_global_load_lds((const __attribute__((address_space(1))) void*)(g),     \
                                   (__attribute__((address_space(3))) void*)(l), 16, 0, 0)

// raw barrier with compiler memory fences on both sides
#define BAR()                                  \
  do {                                         \
    asm volatile("" ::: "memory");             \
    __builtin_amdgcn_s_barrier();              \
    asm volatile("" ::: "memory");             \
  } while (0)

// ---------------- K0a: x fp32 -> bf16 ----------------
__global__ void convert_x(const float* __restrict__ x, u16* __restrict__ xb) {
  size_t i = ((size_t)blockIdx.x * 256 + threadIdx.x) * 4;
  float4 f = *(const float4*)(x + i);
  ushort4 o;
  o.x = f2b(f.x); o.y = f2b(f.y); o.z = f2b(f.z); o.w = f2b(f.w);
  *(ushort4*)(xb + i) = o;
}

// ---------------- K0b: weights fp32 -> bf16 (natural [o][e] layout) ----------------
__global__ void convert_w(const float* __restrict__ Wq, const float* __restrict__ Wk,
                          const float* __restrict__ Wv, const float* __restrict__ Wo,
                          u16* __restrict__ Wqkv, u16* __restrict__ Wob) {
  int idx = (blockIdx.x * 256 + threadIdx.x) * 4;
  int row = idx >> 9;
  int col = idx & 511;
  const float* src = (row < 512)    ? Wq + (size_t)row * 512
                     : (row < 1024) ? Wk + (size_t)(row - 512) * 512
                     : (row < 1536) ? Wv + (size_t)(row - 1024) * 512
                                    : Wo + (size_t)(row - 1536) * 512;
  u16* dst = (row < 1536) ? Wqkv + (size_t)row * 512 : Wob + (size_t)(row - 1536) * 512;
  float4 f = *(const float4*)(src + col);
  ushort4 o;
  o.x = f2b(f.x); o.y = f2b(f.y); o.z = f2b(f.z); o.w = f2b(f.w);
  *(ushort4*)(dst + col) = o;
}

// ============ 256x256 8-phase pipelined GEMM core (m201 port; K1 and K3) ============
// 512 threads = 8 waves (2M x 4N), per-wave C = 128x64. BK=64, K=512 -> 8 K-steps,
// 4 iterations x (2 K-steps, 8 phases). LDS = 2 bufs x (A 256x64 + B 256x64) = 128KB.
// Per phase: {ds_read frag subtile | stage 1 half-tile (2 gload_lds)} -> barrier ->
// 16 MFMA (setprio) -> barrier. vmcnt(4) ONLY at phases 4/8 (waits exactly the next
// K-step's 8 loads; keeps 4 in flight). Stage targets are consumed-before-staged:
// B-halves of a buf are fully read by p2 (staged p3/p4), A-halves by p3 (staged p5/p6);
// each phase's reads drain (lgkm) before its closing barrier, stages issue after it.
// Swizzle: row = 64 u16 = 128 B; granule g(16B) read at (kk*4+qd)^(lr&7) -> 2 rows/slot
// = conflict-free. gload_lds writes wave-contig (base+lane*16): lane covers
// (row = +lane>>3, g = lane&7), so global src granule = (lane&7)^(lane>>3) (involution).

#define LDSV(off) (*(const short8*)&S[(off)])

#define STG(gp, scol, dst)                              \
  do {                                                  \
    ASYNC_LD16((gp) + (scol), S + (dst));               \
    ASYNC_LD16((gp) + (scol) + 4096, S + (dst) + 512);  \
  } while (0)

#define MFMA_CL(MB, JB)                                                                     \
  do {                                                                                      \
    __builtin_amdgcn_s_setprio(1);                                                          \
    _Pragma("unroll") for (int m_ = 0; m_ < 4; ++m_)                                        \
      _Pragma("unroll") for (int j_ = 0; j_ < 2; ++j_) {                                    \
        acc[(MB) + m_][(JB) + j_] = __builtin_amdgcn_mfma_f32_16x16x32_bf16(                \
            aq[m_][0], bf[(JB) + j_][0], acc[(MB) + m_][(JB) + j_], 0, 0, 0);               \
        acc[(MB) + m_][(JB) + j_] = __builtin_amdgcn_mfma_f32_16x16x32_bf16(                \
            aq[m_][1], bf[(JB) + j_][1], acc[(MB) + m_][(JB) + j_], 0, 0, 0);               \
      }                                                                                     \
    __builtin_amdgcn_s_setprio(0);                                                          \
  } while (0)

#define KSTEP(BUF, SG1, SG2, SG3, SG4, BND)                                                  \
  do {                                                                                       \
    short8 aq[4][2], bf[4][2];                                                               \
    /* p1: A-quad0 (8 reads) + B j01 (4 reads) */                                            \
    _Pragma("unroll") for (int m_ = 0; m_ < 4; ++m_) {                                       \
      aq[m_][0] = LDSV((BUF) + rA0 + m_ * 1024);                                             \
      aq[m_][1] = LDSV((BUF) + rA1 + m_ * 1024);                                             \
    }                                                                                        \
    _Pragma("unroll") for (int j_ = 0; j_ < 2; ++j_) {                                       \
      bf[j_][0] = LDSV((BUF) + rB0 + j_ * 1024);                                             \
      bf[j_][1] = LDSV((BUF) + rB1 + j_ * 1024);                                             \
    }                                                                                        \
    SG1;                                                                                     \
    BAR(); MFMA_CL(0, 0); BAR();                                                             \
    /* p2: B j23 (4 reads) */                                                                \
    _Pragma("unroll") for (int j_ = 0; j_ < 2; ++j_) {                                       \
      bf[2 + j_][0] = LDSV((BUF) + rB0 + (2 + j_) * 1024);                                   \
      bf[2 + j_][1] = LDSV((BUF) + rB1 + (2 + j_) * 1024);                                   \
    }                                                                                        \
    SG2; BAR(); MFMA_CL(0, 2); BAR();                                                        \
    /* p3: A-quad1 (8 reads, reuse aq — quad0 dead after p2) */                              \
    _Pragma("unroll") for (int m_ = 0; m_ < 4; ++m_) {                                       \
      aq[m_][0] = LDSV((BUF) + rA0 + (4 + m_) * 1024);                                       \
      aq[m_][1] = LDSV((BUF) + rA1 + (4 + m_) * 1024);                                       \
    }                                                                                        \
    SG3; BAR(); MFMA_CL(4, 2); BAR();                                                        \
    /* p4: no reads */                                                                       \
    SG4; BAR(); MFMA_CL(4, 0); BND; BAR();                                                   \
  } while (0)

// Prologue: K0 all 4 halves + K1 B halves; vmcnt(4) waits K0's 8 loads.
// Steady boundaries: KSTEP(0)'s BND lands K(2i+1) fully (buf1), keeps K(2i+2)-B in
// flight; KSTEP(32768)'s BND lands K(2i+2) fully (buf0), keeps K(2i+3)-B in flight.
// i=3: drain with vmcnt(0).
#define GEMM8_LOOP()                                                                         \
  STG(gB0, 0, dB0); STG(gB1, 0, dB1);                                                        \
  STG(gA0, 0, dA0); STG(gA1, 0, dA1);                                                        \
  STG(gB0, 64, 32768 + dB0); STG(gB1, 64, 32768 + dB1);                                      \
  asm volatile("s_waitcnt vmcnt(4)" ::: "memory");                                           \
  BAR();                                                                                     \
  _Pragma("unroll") for (int i = 0; i < 4; ++i) {                                            \
    const int s1c = (2 * i + 1) * 64, s2c = (2 * i + 2) * 64, s3c = (2 * i + 3) * 64;        \
    if (i < 3) {                                                                             \
      KSTEP(0,                                                                               \
            STG(gA0, s1c, 32768 + dA0),                                                      \
            STG(gA1, s1c, 32768 + dA1),                                                      \
            STG(gB0, s2c, dB0),                                                              \
            STG(gB1, s2c, dB1),                                                              \
            asm volatile("s_waitcnt vmcnt(4)" ::: "memory"));                                \
      KSTEP(32768,                                                                           \
            STG(gA0, s2c, dA0),                                                              \
            STG(gA1, s2c, dA1),                                                              \
            STG(gB0, s3c, 32768 + dB0),                                                      \
            STG(gB1, s3c, 32768 + dB1),                                                      \
            asm volatile("s_waitcnt vmcnt(4)" ::: "memory"));                                \
    } else {                                                                                 \
      KSTEP(0,                                                                               \
            STG(gA0, s1c, 32768 + dA0),                                                      \
            STG(gA1, s1c, 32768 + dA1),                                                      \
            (void)0, (void)0,                                                                \
            asm volatile("s_waitcnt vmcnt(0)" ::: "memory"));                                \
      KSTEP(32768, (void)0, (void)0, (void)0, (void)0, (void)0);                             \
    }                                                                                        \
  }

// ---------------- K1: fused QKV projection ----------------
// Q written token-major [tok][512]; K,V written TRANSPOSED per (b,r): [br][chan][tok]
__global__ __launch_bounds__(512, 2) void gemm_qkv(
    const u16* __restrict__ xb, const u16* __restrict__ Wqkv,
    const float* __restrict__ bq, const float* __restrict__ bk,
    const float* __restrict__ bv, u16* __restrict__ Qb,
    u16* __restrict__ Ktg, u16* __restrict__ Vtg) {
  __shared__ u16 S[65536];  // 128 KB: 2 bufs x (A 256x64 + B 256x64) bf16
  const int tid = threadIdx.x;
  // XCD-bijective swizzle: nwg = 1536 = 8 * 192; 6 consecutive wgs share an A panel.
  const int bid = blockIdx.x;
  const int wg = (bid & 7) * 192 + (bid >> 3);
  const int mtile = wg / 6;
  const int ntile = wg - mtile * 6;
  const int blockM = mtile << 8;
  const int blockN = ntile << 8;

  const int lane = tid & 63;
  const int w = tid >> 6;
  const int wm = (w >> 2) << 7;  // 0 / 128
  const int wn = (w & 3) << 6;   // 0 / 64 / 128 / 192
  const int lr = lane & 15;
  const int qd = lane >> 4;
  const int r7 = lr & 7;
  const int l8 = lane >> 3;
  const int l7 = lane & 7;

  // staging: wave-load (w,l) covers 8 rows; lane -> (row += lane>>3, granule = lane&7);
  // global src granule pre-swizzled: (lane&7) ^ (lane>>3)
  const int gsw8 = (l7 ^ l8) * 8;
  const u16* gA0 = xb + (size_t)(blockM + w * 16 + l8) * 512 + gsw8;   // A half0 (l1:+4096)
  const u16* gA1 = gA0 + 128 * 512;                                    // A half1
  const u16* gB0 = Wqkv + (size_t)(blockN + w * 16 + l8) * 512 + gsw8;
  const u16* gB1 = gB0 + 128 * 512;
  const int dA0 = (w * 16 + l8) * 64 + l7 * 8;   // LDS dest (u16), l1: +512
  const int dA1 = dA0 + 8192;
  const int dB0 = dA0 + 16384;
  const int dB1 = dA0 + 24576;

  // frag read offsets: row*64 + ((kk*4+qd)^(lr&7))*8
  const int rA0 = (wm + lr) * 64 + ((qd) ^ r7) * 8;
  const int rA1 = (wm + lr) * 64 + ((qd + 4) ^ r7) * 8;
  const int rB0 = 16384 + (wn + lr) * 64 + ((qd) ^ r7) * 8;
  const int rB1 = 16384 + (wn + lr) * 64 + ((qd + 4) ^ r7) * 8;

  f32x4 acc[8][4];
#pragma unroll
  for (int m = 0; m < 8; ++m)
#pragma unroll
    for (int j = 0; j < 4; ++j) acc[m][j] = {0.f, 0.f, 0.f, 0.f};

  GEMM8_LOOP();

  // ---------------- epilogue ----------------
  const int which = blockN >> 9;   // ntile 0,1 -> Q; 2,3 -> K; 4,5 -> V
  const int cb = blockN & 511;
  if (which == 0) {
    // Q: token-major, elu+1
#pragma unroll
    for (int j = 0; j < 4; ++j) {
      int col = cb + wn + j * 16 + lr;
      float bsv = bq[col];
#pragma unroll
      for (int m = 0; m < 8; ++m) {
        int row = blockM + wm + m * 16 + qd * 4;
#pragma unroll
        for (int r = 0; r < 4; ++r) {
          float v = acc[m][j][r] + bsv;
          v = (v > 0.f) ? v + 1.f : __expf(v);
          Qb[(size_t)(row + r) * 512 + col] = f2b(v);
        }
      }
    }
  } else {
    // K/V: transposed store [br][chan][tok], elu+1 for K only
    u16* dstT = (which == 1) ? Ktg : Vtg;
    const float* bias = (which == 1) ? bk : bv;
    const int br = blockM >> 9;
    const int t0 = (blockM & 511) + wm;
#pragma unroll
    for (int j = 0; j < 4; ++j) {
      int col = cb + wn + j * 16 + lr;
      float bsv = bias[col];
      size_t rowbase = (size_t)br * 262144 + (size_t)col * 512;
#pragma unroll
      for (int m = 0; m < 8; ++m) {
        int c0 = t0 + m * 16 + qd * 4;
        float v0 = acc[m][j][0] + bsv, v1 = acc[m][j][1] + bsv;
        float v2 = acc[m][j][2] + bsv, v3 = acc[m][j][3] + bsv;
        if (which == 1) {
          v0 = (v0 > 0.f) ? v0 + 1.f : __expf(v0);
          v1 = (v1 > 0.f) ? v1 + 1.f : __expf(v1);
          v2 = (v2 > 0.f) ? v2 + 1.f : __expf(v2);
          v3 = (v3 > 0.f) ? v3 + 1.f : __expf(v3);
        }
        ushort4 p;
        p.x = f2b(v0); p.y = f2b(v1); p.z = f2b(v2); p.w = f2b(v3);
        *(ushort4*)&dstT[rowbase + c0] = p;
      }
    }
  }
}

// ---------------- K2: per (b,r,h): ktv, ksum, z, out_h — MFMA version ----------------
// Ktg/Vtg are [br][512 chan][512 tok]; Qb token-major; Hb token-major.
__global__ void attn(const u16* __restrict__ Qb, const u16* __restrict__ Ktg,
                     const u16* __restrict__ Vtg, u16* __restrict__ Hb) {
  __shared__ u16 KtS[64 * 32];     // [d][32 c]
  __shared__ u16 VtS[64 * 32];     // [e][32 c]
  __shared__ u16 QS[2 * 128 * 32]; // [kc][tok][32 d]
  __shared__ u16 ktvT[2 * 64 * 32];// [kc][e][32 d]  (bf16)
  __shared__ float part[256];
  __shared__ float ksumf[64];
  __shared__ float zs[128];

  const int tid = threadIdx.x;
  const int br = blockIdx.x >> 3;
  const int h = blockIdx.x & 7;
  const int h64 = h * 64;
  const size_t tok0 = (size_t)br * 512;
  const size_t tbase = (size_t)br * 262144 + (size_t)h64 * 512;

  const int lane = tid & 63;
  const int w = tid >> 6;
  const int lr = lane & 15;
  const int qd = lane >> 4;

  const int sc_chan = tid >> 2, sc_seg = tid & 3;  // staging: 64 chans x 4 segs of 8

  // ---------- phase A: ktv = K^T V (wave w owns d-strip [w*16, w*16+16)) ----------
  f32x4 acc[4];
#pragma unroll
  for (int j = 0; j < 4; ++j) acc[j] = {0.f, 0.f, 0.f, 0.f};
  float ks = 0.f;

  for (int ct = 0; ct < 16; ++ct) {
    __syncthreads();
    {
      size_t g = tbase + (size_t)sc_chan * 512 + ct * 32 + sc_seg * 8;
      ASYNC_LD16(Ktg + g, KtS + tid * 8);
      ASYNC_LD16(Vtg + g, VtS + tid * 8);
    }
    __syncthreads();
    short8 a = *(const short8*)&KtS[(w * 16 + lr) * 32 + qd * 8];
#pragma unroll
    for (int j = 0; j < 4; ++j) {
      short8 b = *(const short8*)&VtS[(j * 16 + lr) * 32 + qd * 8];
      acc[j] = __builtin_amdgcn_mfma_f32_16x16x32_bf16(a, b, acc[j], 0, 0, 0);
    }
    // ksum partial: thread owns (d = tid>>2, quarter cq = tid&3)
    ushort4 k0 = *(const ushort4*)&KtS[sc_chan * 32 + sc_seg * 8];
    ushort4 k1 = *(const ushort4*)&KtS[sc_chan * 32 + sc_seg * 8 + 4];
    ks += b2f(k0.x) + b2f(k0.y) + b2f(k0.z) + b2f(k0.w)
        + b2f(k1.x) + b2f(k1.y) + b2f(k1.z) + b2f(k1.w);
  }
  part[tid] = ks;
  // write ktvT [kc = w>>1][e][d' = (w&1)*16 + qd*4 + r] as bf16
  {
    int kc = w >> 1;
    int dp = (w & 1) * 16 + qd * 4;
#pragma unroll
    for (int j = 0; j < 4; ++j) {
      int e = j * 16 + lr;
      ushort4 p;
      p.x = f2b(acc[j][0]); p.y = f2b(acc[j][1]);
      p.z = f2b(acc[j][2]); p.w = f2b(acc[j][3]);
      *(ushort4*)&ktvT[kc * 2048 + e * 32 + dp] = p;
    }
  }
  __syncthreads();
  if (tid < 64)
    ksumf[tid] = part[tid * 4] + part[tid * 4 + 1] + part[tid * 4 + 2] + part[tid * 4 + 3];
  __syncthreads();

  // hoist B-fragments (ktv) — loop-invariant
  short8 bfr[4][2];
#pragma unroll
  for (int j = 0; j < 4; ++j)
#pragma unroll
    for (int kc = 0; kc < 2; ++kc)
      bfr[j][kc] = *(const short8*)&ktvT[kc * 2048 + (j * 16 + lr) * 32 + qd * 8];

  // ---------- phase B: out = (Q @ ktv) * z, 4 chunks of 128 tokens ----------
  for (int ct = 0; ct < 4; ++ct) {
    __syncthreads();
#pragma unroll
    for (int kc = 0; kc < 2; ++kc)
#pragma unroll
      for (int half = 0; half < 2; ++half)
        ASYNC_LD16(Qb + (tok0 + ct * 128 + half * 64 + sc_chan) * 512 + h64 + kc * 32 + sc_seg * 8,
                   QS + kc * 4096 + half * 2048 + tid * 8);
    __syncthreads();
    // z per token (skewed LDS walk, conflict-free)
    if (tid < 128) {
      float s = 0.f;
#pragma unroll 8
      for (int i = 0; i < 32; ++i) {
        int ix = (i + tid) & 31;
        s += b2f(QS[tid * 32 + ix]) * ksumf[ix];
        s += b2f(QS[4096 + tid * 32 + ix]) * ksumf[32 + ix];
      }
      zs[tid] = 1.f / (s + 1e-6f);
    }
    __syncthreads();
    // MFMA: wave w owns token strips (w*2+s)*16
#pragma unroll
    for (int s = 0; s < 2; ++s) {
      int mrow = (w * 2 + s) * 16 + lr;
      short8 a0 = *(const short8*)&QS[mrow * 32 + qd * 8];
      short8 a1 = *(const short8*)&QS[4096 + mrow * 32 + qd * 8];
      f32x4 o[4];
#pragma unroll
      for (int j = 0; j < 4; ++j) {
        o[j] = {0.f, 0.f, 0.f, 0.f};
        o[j] = __builtin_amdgcn_mfma_f32_16x16x32_bf16(a0, bfr[j][0], o[j], 0, 0, 0);
        o[j] = __builtin_amdgcn_mfma_f32_16x16x32_bf16(a1, bfr[j][1], o[j], 0, 0, 0);
      }
      int tl = (w * 2 + s) * 16 + qd * 4;
      float z0 = zs[tl], z1 = zs[tl + 1], z2 = zs[tl + 2], z3 = zs[tl + 3];
      size_t gb = (tok0 + ct * 128 + tl) * 512 + h64;
#pragma unroll
      for (int j = 0; j < 4; ++j) {
        int e = j * 16 + lr;
        Hb[gb + e] = f2b(o[j][0] * z0);
        Hb[gb + 512 + e] = f2b(o[j][1] * z1);
        Hb[gb + 1024 + e] = f2b(o[j][2] * z2);
        Hb[gb + 1536 + e] = f2b(o[j][3] * z3);
      }
    }
  }
}

// ---------------- K3: out = out_h @ Wo^T + bo (fp32 out) ----------------
__global__ __launch_bounds__(512, 2) void gemm_out(
    const u16* __restrict__ Hb, const u16* __restrict__ Wob,
    const float* __restrict__ bo, float* __restrict__ out) {
  __shared__ u16 S[65536];
  const int tid = threadIdx.x;
  // XCD-bijective swizzle: nwg = 512 = 8 * 64
  const int bid = blockIdx.x;
  const int wg = (bid & 7) * 64 + (bid >> 3);
  const int mtile = wg >> 1;
  const int ntile = wg & 1;
  const int blockM = mtile << 8;
  const int blockN = ntile << 8;

  const int lane = tid & 63;
  const int w = tid >> 6;
  const int wm = (w >> 2) << 7;
  const int wn = (w & 3) << 6;
  const int lr = lane & 15;
  const int qd = lane >> 4;
  const int r7 = lr & 7;
  const int l8 = lane >> 3;
  const int l7 = lane & 7;

  const int gsw8 = (l7 ^ l8) * 8;
  const u16* gA0 = Hb + (size_t)(blockM + w * 16 + l8) * 512 + gsw8;
  const u16* gA1 = gA0 + 128 * 512;
  const u16* gB0 = Wob + (size_t)(blockN + w * 16 + l8) * 512 + gsw8;
  const u16* gB1 = gB0 + 128 * 512;
  const int dA0 = (w * 16 + l8) * 64 + l7 * 8;
  const int dA1 = dA0 + 8192;
  const int dB0 = dA0 + 16384;
  const int dB1 = dA0 + 24576;

  const int rA0 = (wm + lr) * 64 + ((qd) ^ r7) * 8;
  const int rA1 = (wm + lr) * 64 + ((qd + 4) ^ r7) * 8;
  const int rB0 = 16384 + (wn + lr) * 64 + ((qd) ^ r7) * 8;
  const int rB1 = 16384 + (wn + lr) * 64 + ((qd + 4) ^ r7) * 8;

  f32x4 acc[8][4];
#pragma unroll
  for (int m = 0; m < 8; ++m)
#pragma unroll
    for (int j = 0; j < 4; ++j) acc[m][j] = {0.f, 0.f, 0.f, 0.f};

  GEMM8_LOOP();

#pragma unroll
  for (int j = 0; j < 4; ++j) {
    int col = blockN + wn + j * 16 + lr;
    float bsv = bo[col];
#pragma unroll
    for (int m = 0; m < 8; ++m) {
      int row = blockM + wm + m * 16 + qd * 4;
#pragma unroll
      for (int r = 0; r < 4; ++r)
        out[(size_t)(row + r) * 512 + col] = acc[m][j][r] + bsv;
    }
  }
}

// ---------------- launch ----------------
extern "C" void kernel_launch(void* const* d_in, const int* in_sizes, int n_in,
                              void* d_out, int out_size, void* d_ws, size_t ws_size,
                              hipStream_t stream) {
  const float* x  = (const float*)d_in[0];
  const float* Wq = (const float*)d_in[1];
  const float* bq = (const float*)d_in[2];
  const float* Wk = (const float*)d_in[3];
  const float* bk = (const float*)d_in[4];
  const float* Wv = (const float*)d_in[5];
  const float* bv = (const float*)d_in[6];
  const float* Wo = (const float*)d_in[7];
  const float* bo = (const float*)d_in[8];
  float* out = (float*)d_out;

  char* ws = (char*)d_ws;
  u16* xb   = (u16*)(ws);                 // 64 MB  (reused as Hb)
  u16* Wqkv = (u16*)(ws + 0x04000000ull); // 1.5 MB
  u16* Wob  = (u16*)(ws + 0x04200000ull); // 0.5 MB
  u16* Qb   = (u16*)(ws + 0x04400000ull); // 64 MB
  u16* Ktg  = (u16*)(ws + 0x08400000ull); // 64 MB [br][chan][tok]
  u16* Vtg  = (u16*)(ws + 0x0C400000ull); // 64 MB [br][chan][tok]
  u16* Hb   = xb;

  hipLaunchKernelGGL(convert_x, dim3(32768), dim3(256), 0, stream, x, xb);
  hipLaunchKernelGGL(convert_w, dim3(1024), dim3(256), 0, stream, Wq, Wk, Wv, Wo, Wqkv, Wob);
  hipLaunchKernelGGL(gemm_qkv, dim3(1536), dim3(512), 0, stream, xb, Wqkv, bq, bk, bv, Qb, Ktg, Vtg);
  hipLaunchKernelGGL(attn, dim3(1024), dim3(256), 0, stream, Qb, Ktg, Vtg, Hb);
  hipLaunchKernelGGL(gemm_out, dim3(512), dim3(512), 0, stream, Hb, Wob, bo, out);
}